// Round 5
// baseline (434.454 us; speedup 1.0000x reference)
//
#include <hip/hip_runtime.h>
#include <hip/hip_bf16.h>
#include <stdint.h>

#define N_NODES  50000
#define N_GRAPHS 256
#define DIM      128
#define N_EDGES  800000
#define K2       256            // fused K = [agg | h]
#define N_STRIPS (N_NODES / 16) // 3125, exact
#define PAD_CAP  64             // max degree slack (mean 16; fixed edge list, no overflow)
#define NBUCKET  196            // ceil(50000/256) buckets of 256 nodes (bucket = dst>>8)
#define NCHUNK   256            // edge chunks
#define CHUNK    3125           // NCHUNK*CHUNK == N_EDGES exactly

typedef __attribute__((ext_vector_type(8))) short  short8;
typedef __attribute__((ext_vector_type(4))) float  floatx4;

__device__ __forceinline__ ushort f2bf(float f) {
    union { float f; uint32_t u; } c; c.f = f;
    uint32_t u = c.u;
    return (ushort)((u + 0x7fffu + ((u >> 16) & 1u)) >> 16);  // RNE
}
__device__ __forceinline__ float bf2f(ushort b) {
    union { uint32_t u; float f; } c; c.u = ((uint32_t)b) << 16;
    return c.f;
}

// ---------- prep: fp32 x -> bf16 ----------
__global__ __launch_bounds__(256) void k_convert_x(const float* __restrict__ x,
                                                   ushort* __restrict__ xb) {
    int i = blockIdx.x * 256 + threadIdx.x;          // float4 index
    const int n4 = N_NODES * DIM / 4;
    if (i < n4) {
        float4 v = ((const float4*)x)[i];
        uint32_t lo = (uint32_t)f2bf(v.x) | ((uint32_t)f2bf(v.y) << 16);
        uint32_t hi = (uint32_t)f2bf(v.z) | ((uint32_t)f2bf(v.w) << 16);
        ((uint2*)xb)[i] = make_uint2(lo, hi);
    }
}

// ---------- prep: all 3 layers' Wt[n][k] = bf16( k<128 ? Wl[k][n] : Wr[k-128][n] ) ----------
__global__ __launch_bounds__(256) void k_prep_w_all(const float* __restrict__ Wl0, const float* __restrict__ Wr0,
                                                    const float* __restrict__ Wl1, const float* __restrict__ Wr1,
                                                    const float* __restrict__ Wl2, const float* __restrict__ Wr2,
                                                    ushort* __restrict__ Wt) {   // 3 * DIM * K2
    int i = blockIdx.x * 256 + threadIdx.x;
    if (i < 3 * DIM * K2) {
        int layer = i / (DIM * K2);
        int j = i % (DIM * K2);
        int n = j / K2, k = j % K2;
        const float* Wl = (layer == 0) ? Wl0 : (layer == 1) ? Wl1 : Wl2;
        const float* Wr = (layer == 0) ? Wr0 : (layer == 1) ? Wr1 : Wr2;
        float v = (k < DIM) ? Wl[k * DIM + n] : Wr[(k - DIM) * DIM + n];
        Wt[i] = f2bf(v);
    }
}

// ---------- radix bucket build (no global atomics) ----------
// 1) per-chunk bucket histogram (LDS atomics only)
__global__ __launch_bounds__(256) void k_hist(const int* __restrict__ dst,
                                              int* __restrict__ counts) {  // [NCHUNK][NBUCKET]
    __shared__ int hist[NBUCKET];
    int t = threadIdx.x, b = blockIdx.x;
    if (t < NBUCKET) hist[t] = 0;
    __syncthreads();
    const int e0 = b * CHUNK;
    for (int i = t; i < CHUNK; i += 256)
        atomicAdd(&hist[dst[e0 + i] >> 8], 1);
    __syncthreads();
    if (t < NBUCKET) counts[b * NBUCKET + t] = hist[t];
}

// 2) offsets: off[b][j] = base[j] + sum_{b'<b} counts[b'][j]; also total/base per bucket
__global__ __launch_bounds__(256) void k_scan_b(const int* __restrict__ counts,
                                                int* __restrict__ off,      // [NCHUNK][NBUCKET]
                                                int* __restrict__ total,    // [NBUCKET]
                                                int* __restrict__ basep) {  // [NBUCKET]
    __shared__ int sbuf[256];
    int j = threadIdx.x;
    int run = 0;
    if (j < NBUCKET) {
        for (int b = 0; b < NCHUNK; ++b) {          // coalesced across j
            off[b * NBUCKET + j] = run;
            run += counts[b * NBUCKET + j];
        }
        total[j] = run;
    }
    sbuf[j] = (j < NBUCKET) ? run : 0;
    __syncthreads();
    #pragma unroll
    for (int d = 1; d < 256; d <<= 1) {
        int v = (j >= d) ? sbuf[j - d] : 0;
        __syncthreads();
        sbuf[j] += v;
        __syncthreads();
    }
    int base = sbuf[j] - ((j < NBUCKET) ? run : 0); // exclusive
    if (j < NBUCKET) {
        basep[j] = base;
        for (int b = 0; b < NCHUNK; ++b)
            off[b * NBUCKET + j] += base;
    }
}

// 3) scatter packed edges into bucket-contiguous buffer (LDS cursors)
__global__ __launch_bounds__(256) void k_scatter(const int* __restrict__ src,
                                                 const int* __restrict__ dst,
                                                 const int* __restrict__ off,
                                                 uint32_t* __restrict__ ebuf) {
    __shared__ int cur[NBUCKET];
    int t = threadIdx.x, b = blockIdx.x;
    if (t < NBUCKET) cur[t] = off[b * NBUCKET + t];
    __syncthreads();
    const int e0 = b * CHUNK;
    for (int i = t; i < CHUNK; i += 256) {
        int d = dst[e0 + i];
        int s = src[e0 + i];                         // < 50000 < 2^16
        int p = atomicAdd(&cur[d >> 8], 1);
        ebuf[p] = ((uint32_t)(d & 255) << 16) | (uint32_t)s;
    }
}

// 4) per-bucket adjacency build: LDS counters, stores confined to 64KB region
__global__ __launch_bounds__(256) void k_build(const uint32_t* __restrict__ ebuf,
                                               const int* __restrict__ total,
                                               const int* __restrict__ basep,
                                               int* __restrict__ padded,
                                               int* __restrict__ cnt) {
    __shared__ int lcnt[256];
    int t = threadIdx.x, j = blockIdx.x;
    lcnt[t] = 0;
    __syncthreads();
    int b0 = basep[j], tot = total[j];
    for (int i = t; i < tot; i += 256) {
        uint32_t v = ebuf[b0 + i];
        int dl = (int)(v >> 16);
        int s  = (int)(v & 0xffffu);
        int p  = atomicAdd(&lcnt[dl], 1);
        if (p < PAD_CAP) padded[((size_t)j * 256 + dl) * PAD_CAP + p] = s;
    }
    __syncthreads();
    int node = j * 256 + t;
    if (node < N_NODES) cnt[node] = lcnt[t];
}

// ---------- canonicalize adjacency: bitonic sort each node's list across one wave ----------
// Multiset per node is deterministic; sorting makes the summation order (and bf16
// rounding) a deterministic function of the edge set, independent of build order.
__global__ __launch_bounds__(256) void k_sort_adj(int* __restrict__ padded,
                                                  const int* __restrict__ cnt) {
    int wid  = threadIdx.x >> 6;
    int lane = threadIdx.x & 63;
    int node = blockIdx.x * 4 + wid;
    if (node >= N_NODES) return;
    int deg = cnt[node];
    int m   = deg < PAD_CAP ? deg : PAD_CAP;
    int* lst = padded + (size_t)node * PAD_CAP;
    int v = (lane < m) ? lst[lane] : 0x7fffffff;   // pad sorts to the end
    #pragma unroll
    for (int k = 2; k <= 64; k <<= 1) {
        #pragma unroll
        for (int j = k >> 1; j > 0; j >>= 1) {
            int other  = __shfl_xor(v, j, 64);
            bool down  = (lane & k) != 0;
            bool lower = (lane & j) == 0;
            v = (lower ^ down) ? min(v, other) : max(v, other);
        }
    }
    if (lane < m) lst[lane] = v;                   // ascending neighbor ids
}

// ---------- per-graph node ranges from sorted batch (no atomics) ----------
__global__ __launch_bounds__(256) void k_gbounds(const int* __restrict__ batch,
                                                 int* __restrict__ gstart,
                                                 int* __restrict__ gend) {
    int i = blockIdx.x * 256 + threadIdx.x;
    if (i >= N_NODES) return;
    int g = batch[i];
    if (i == 0) gstart[g] = 0;
    int gn = (i + 1 < N_NODES) ? batch[i + 1] : -1;
    if (gn != g) {
        gend[g] = i + 1;
        if (gn >= 0) gstart[gn] = i + 1;
    }
}

// ---------- neighbor mean aggregation (one wave per node, 16-wide MLP) ----------
__global__ __launch_bounds__(256) void k_aggregate(const ushort* __restrict__ h_in,
                                                   const int* __restrict__ padded,
                                                   const int* __restrict__ cnt,
                                                   ushort* __restrict__ agg) {
    int wid  = threadIdx.x >> 6;
    int lane = threadIdx.x & 63;
    int node = blockIdx.x * 4 + wid;
    if (node >= N_NODES) return;
    int deg = cnt[node];
    int m   = deg < PAD_CAP ? deg : PAD_CAP;
    const int* lst = padded + (size_t)node * PAD_CAP;
    const uint32_t* hw = (const uint32_t*)h_in;   // 64 dwords per row
    float ax[4] = {0.f, 0.f, 0.f, 0.f};
    float ay[4] = {0.f, 0.f, 0.f, 0.f};
    for (int e = 0; e < m; e += 16) {
        int idx[16];
        uint32_t v[16];
        #pragma unroll
        for (int k = 0; k < 16; ++k) {
            int ek = e + k;
            idx[k] = lst[ek < m ? ek : m - 1];     // uniform clamp; dup loads hit cache
        }
        #pragma unroll
        for (int k = 0; k < 16; ++k)
            v[k] = hw[(size_t)idx[k] * 64 + lane]; // 16 independent 256B row loads in flight
        #pragma unroll
        for (int k = 0; k < 16; ++k) {
            uint32_t w = (e + k < m) ? v[k] : 0u;  // predicated tail (bf16 +0.0)
            ax[k & 3] += bf2f((ushort)(w & 0xffffu));
            ay[k & 3] += bf2f((ushort)(w >> 16));
        }
    }
    float axs = (ax[0] + ax[1]) + (ax[2] + ax[3]);
    float ays = (ay[0] + ay[1]) + (ay[2] + ay[3]);
    float inv = 1.0f / (float)(deg > 0 ? deg : 1);
    uint32_t o = (uint32_t)f2bf(axs * inv) | ((uint32_t)f2bf(ays * inv) << 16);
    ((uint32_t*)(agg + (size_t)node * DIM))[lane] = o;
}

// ---------- fused SAGE GEMM: h_out = relu([agg|h] @ [Wl;Wr] + bl) ----------
template <bool OUT_F32>
__global__ __launch_bounds__(256) void k_gemm(const ushort* __restrict__ agg,
                                              const ushort* __restrict__ h_in,
                                              const ushort* __restrict__ Wt,
                                              const float* __restrict__ bias,
                                              ushort* __restrict__ out_bf,
                                              float* __restrict__ out_f) {
    int wid   = threadIdx.x >> 6;
    int lane  = threadIdx.x & 63;
    int strip = blockIdx.x * 4 + wid;
    if (strip >= N_STRIPS) return;
    int r0   = strip * 16;
    int row  = lane & 15;
    int quad = lane >> 4;
    int mrow = r0 + row;

    // A fragments: lane holds A[m=lane&15][k=quad*8+j], j=0..7  (16B contiguous)
    short8 a[8];
    const ushort* arow = agg  + (size_t)mrow * DIM + quad * 8;
    const ushort* hrow = h_in + (size_t)mrow * DIM + quad * 8;
    #pragma unroll
    for (int ks = 0; ks < 4; ++ks) a[ks]     = *(const short8*)(arow + ks * 32);
    #pragma unroll
    for (int ks = 0; ks < 4; ++ks) a[4 + ks] = *(const short8*)(hrow + ks * 32);

    #pragma unroll
    for (int ct = 0; ct < 8; ++ct) {
        int col = ct * 16 + row;
        const ushort* wrow = Wt + (size_t)col * K2 + quad * 8;
        floatx4 acc = {0.f, 0.f, 0.f, 0.f};
        #pragma unroll
        for (int ks = 0; ks < 8; ++ks) {
            short8 b = *(const short8*)(wrow + ks * 32);
            acc = __builtin_amdgcn_mfma_f32_16x16x32_bf16(a[ks], b, acc, 0, 0, 0);
        }
        float bv = bias[col];
        #pragma unroll
        for (int r = 0; r < 4; ++r) {
            int m = r0 + quad * 4 + r;           // C/D: col=lane&15, row=quad*4+reg
            float v = acc[r] + bv;
            v = v > 0.f ? v : 0.f;
            if (OUT_F32) out_f[(size_t)m * DIM + col] = v;
            else         out_bf[(size_t)m * DIM + col] = f2bf(v);
        }
    }
}

// ---------- mean/max readout (batch sorted -> run-length flush) ----------
__global__ __launch_bounds__(128) void k_readout(const float* __restrict__ h,
                                                 const int* __restrict__ batch,
                                                 float* __restrict__ out) {
    int d  = threadIdx.x;                 // 0..127
    int n0 = blockIdx.x * 128;
    int n1 = min(n0 + 128, N_NODES);
    int cur = -1; float sum = 0.f, mx = 0.f;
    for (int i = n0; i < n1; ++i) {
        int g = batch[i];                 // block-uniform
        if (g != cur) {
            if (cur >= 0) {
                atomicAdd(&out[cur * 2 * DIM + d], sum);
                atomicMax((int*)&out[cur * 2 * DIM + DIM + d], __float_as_int(mx));
            }
            cur = g; sum = 0.f; mx = 0.f;
        }
        float v = h[(size_t)i * DIM + d];
        sum += v; mx = fmaxf(mx, v);
    }
    if (cur >= 0) {
        atomicAdd(&out[cur * 2 * DIM + d], sum);
        atomicMax((int*)&out[cur * 2 * DIM + DIM + d], __float_as_int(mx));
    }
}

__global__ __launch_bounds__(256) void k_finalize(float* __restrict__ out,
                                                  const int* __restrict__ gstart,
                                                  const int* __restrict__ gend) {
    int i = blockIdx.x * 256 + threadIdx.x;
    if (i < N_GRAPHS * DIM) {
        int g = i / DIM, d = i % DIM;
        int c = gend[g] - gstart[g];
        out[g * 2 * DIM + d] /= (float)(c > 0 ? c : 1);
    }
}

extern "C" void kernel_launch(void* const* d_in, const int* in_sizes, int n_in,
                              void* d_out, int out_size, void* d_ws, size_t ws_size,
                              hipStream_t stream) {
    const float* x     = (const float*)d_in[0];
    const int*   ei    = (const int*)d_in[1];
    const int*   src   = ei;
    const int*   dst   = ei + N_EDGES;
    const int*   batch = (const int*)d_in[2];
    const float* Wl[3] = {(const float*)d_in[3], (const float*)d_in[6], (const float*)d_in[9]};
    const float* bl[3] = {(const float*)d_in[4], (const float*)d_in[7], (const float*)d_in[10]};
    const float* Wr[3] = {(const float*)d_in[5], (const float*)d_in[8], (const float*)d_in[11]};
    float* out = (float*)d_out;

    char* base = (char*)d_ws;
    size_t o = 0;
    auto alloc = [&](size_t b) -> char* {
        char* p = base + o;
        o = (o + b + 255) & ~(size_t)255;
        return p;
    };
    int*     gstart = (int*)alloc((size_t)N_GRAPHS * 4);
    int*     gend   = (int*)alloc((size_t)N_GRAPHS * 4);
    size_t   zero_bytes = o;                      // gstart+gend contiguous
    int*     cnt    = (int*)alloc((size_t)N_NODES * 4);
    int*     counts = (int*)alloc((size_t)NCHUNK * NBUCKET * 4);
    int*     offs   = (int*)alloc((size_t)NCHUNK * NBUCKET * 4);
    int*     total  = (int*)alloc((size_t)NBUCKET * 4);
    int*     basep  = (int*)alloc((size_t)NBUCKET * 4);
    uint32_t* ebuf  = (uint32_t*)alloc((size_t)N_EDGES * 4);
    int*     padded = (int*)alloc((size_t)N_NODES * PAD_CAP * 4);    // 12.8 MB
    ushort*  xb     = (ushort*)alloc((size_t)N_NODES * DIM * 2);
    ushort*  ha     = (ushort*)alloc((size_t)N_NODES * DIM * 2);
    ushort*  hb     = (ushort*)alloc((size_t)N_NODES * DIM * 2);
    ushort*  agg    = (ushort*)alloc((size_t)N_NODES * DIM * 2);
    float*   h3     = (float*)alloc((size_t)N_NODES * DIM * 4);
    ushort*  Wt     = (ushort*)alloc((size_t)3 * DIM * K2 * 2);
    (void)ws_size; (void)n_in; (void)in_sizes;

    hipMemsetAsync(base, 0, zero_bytes, stream);
    hipMemsetAsync(d_out, 0, (size_t)out_size * 4, stream);

    k_convert_x<<<(N_NODES * DIM / 4 + 255) / 256, 256, 0, stream>>>(x, xb);
    k_prep_w_all<<<(3 * DIM * K2 + 255) / 256, 256, 0, stream>>>(
        Wl[0], Wr[0], Wl[1], Wr[1], Wl[2], Wr[2], Wt);

    k_hist<<<NCHUNK, 256, 0, stream>>>(dst, counts);
    k_scan_b<<<1, 256, 0, stream>>>(counts, offs, total, basep);
    k_scatter<<<NCHUNK, 256, 0, stream>>>(src, dst, offs, ebuf);
    k_build<<<NBUCKET, 256, 0, stream>>>(ebuf, total, basep, padded, cnt);
    k_sort_adj<<<(N_NODES + 3) / 4, 256, 0, stream>>>(padded, cnt);
    k_gbounds<<<(N_NODES + 255) / 256, 256, 0, stream>>>(batch, gstart, gend);

    const int aggGrid  = (N_NODES + 3) / 4;
    const int gemmGrid = (N_STRIPS + 3) / 4;

    // layer 0
    k_aggregate<<<aggGrid, 256, 0, stream>>>(xb, padded, cnt, agg);
    k_gemm<false><<<gemmGrid, 256, 0, stream>>>(agg, xb, Wt, bl[0], ha, nullptr);
    // layer 1
    k_aggregate<<<aggGrid, 256, 0, stream>>>(ha, padded, cnt, agg);
    k_gemm<false><<<gemmGrid, 256, 0, stream>>>(agg, ha, Wt + DIM * K2, bl[1], hb, nullptr);
    // layer 2 (fp32 output for readout accuracy)
    k_aggregate<<<aggGrid, 256, 0, stream>>>(hb, padded, cnt, agg);
    k_gemm<true><<<gemmGrid, 256, 0, stream>>>(agg, hb, Wt + 2 * DIM * K2, bl[2], nullptr, h3);

    k_readout<<<(N_NODES + 127) / 128, 128, 0, stream>>>(h3, batch, out);
    k_finalize<<<(N_GRAPHS * DIM + 255) / 256, 256, 0, stream>>>(out, gstart, gend);
}

// Round 6
// 386.530 us; speedup vs baseline: 1.1240x; 1.1240x over previous
//
#include <hip/hip_runtime.h>
#include <hip/hip_bf16.h>
#include <stdint.h>

#define N_NODES  50000
#define N_GRAPHS 256
#define DIM      128
#define N_EDGES  800000
#define K2       256            // fused K = [agg | h]
#define N_STRIPS (N_NODES / 16) // 3125, exact
#define PAD_CAP  64             // max degree slack (mean 16; fixed edge list, no overflow)
#define NBUCKET  196            // ceil(50000/256) buckets of 256 nodes (bucket = dst>>8)
#define NCHUNK   256            // edge chunks
#define CHUNK    3125           // NCHUNK*CHUNK == N_EDGES exactly

typedef __attribute__((ext_vector_type(8))) short  short8;
typedef __attribute__((ext_vector_type(4))) float  floatx4;

__device__ __forceinline__ ushort f2bf(float f) {
    union { float f; uint32_t u; } c; c.f = f;
    uint32_t u = c.u;
    return (ushort)((u + 0x7fffu + ((u >> 16) & 1u)) >> 16);  // RNE
}
__device__ __forceinline__ float bf2f(ushort b) {
    union { uint32_t u; float f; } c; c.u = ((uint32_t)b) << 16;
    return c.f;
}

// ---------- prep: fp32 x -> bf16 ----------
__global__ __launch_bounds__(256) void k_convert_x(const float* __restrict__ x,
                                                   ushort* __restrict__ xb) {
    int i = blockIdx.x * 256 + threadIdx.x;          // float4 index
    const int n4 = N_NODES * DIM / 4;
    if (i < n4) {
        float4 v = ((const float4*)x)[i];
        uint32_t lo = (uint32_t)f2bf(v.x) | ((uint32_t)f2bf(v.y) << 16);
        uint32_t hi = (uint32_t)f2bf(v.z) | ((uint32_t)f2bf(v.w) << 16);
        ((uint2*)xb)[i] = make_uint2(lo, hi);
    }
}

// ---------- prep: all 3 layers' Wt[n][k] = bf16( k<128 ? Wl[k][n] : Wr[k-128][n] ) ----------
__global__ __launch_bounds__(256) void k_prep_w_all(const float* __restrict__ Wl0, const float* __restrict__ Wr0,
                                                    const float* __restrict__ Wl1, const float* __restrict__ Wr1,
                                                    const float* __restrict__ Wl2, const float* __restrict__ Wr2,
                                                    ushort* __restrict__ Wt) {   // 3 * DIM * K2
    int i = blockIdx.x * 256 + threadIdx.x;
    if (i < 3 * DIM * K2) {
        int layer = i / (DIM * K2);
        int j = i % (DIM * K2);
        int n = j / K2, k = j % K2;
        const float* Wl = (layer == 0) ? Wl0 : (layer == 1) ? Wl1 : Wl2;
        const float* Wr = (layer == 0) ? Wr0 : (layer == 1) ? Wr1 : Wr2;
        float v = (k < DIM) ? Wl[k * DIM + n] : Wr[(k - DIM) * DIM + n];
        Wt[i] = f2bf(v);
    }
}

// ---------- radix bucket build (no global atomics) ----------
// 1) per-chunk bucket histogram (LDS atomics only)
__global__ __launch_bounds__(256) void k_hist(const int* __restrict__ dst,
                                              int* __restrict__ counts) {  // [NCHUNK][NBUCKET]
    __shared__ int hist[NBUCKET];
    int t = threadIdx.x, b = blockIdx.x;
    if (t < NBUCKET) hist[t] = 0;
    __syncthreads();
    const int e0 = b * CHUNK;
    for (int i = t; i < CHUNK; i += 256)
        atomicAdd(&hist[dst[e0 + i] >> 8], 1);
    __syncthreads();
    if (t < NBUCKET) counts[b * NBUCKET + t] = hist[t];
}

// 2a) per-bucket-column parallel scan over chunks: off[b][j] = sum_{b'<b} counts[b'][j]
__global__ __launch_bounds__(256) void k_scan_col(const int* __restrict__ counts,
                                                  int* __restrict__ off,     // [NCHUNK][NBUCKET]
                                                  int* __restrict__ total) { // [NBUCKET]
    __shared__ int buf[256];
    int t = threadIdx.x, j = blockIdx.x;            // j < NBUCKET
    int v = counts[t * NBUCKET + j];
    buf[t] = v;
    __syncthreads();
    #pragma unroll
    for (int d = 1; d < 256; d <<= 1) {
        int x = (t >= d) ? buf[t - d] : 0;
        __syncthreads();
        buf[t] += x;
        __syncthreads();
    }
    off[t * NBUCKET + j] = buf[t] - v;              // exclusive within column
    if (t == 255) total[j] = buf[255];
}

// 2b) exclusive scan of bucket totals -> bucket base addresses
__global__ __launch_bounds__(256) void k_scan_total(const int* __restrict__ total,
                                                    int* __restrict__ basep) {
    __shared__ int buf[256];
    int t = threadIdx.x;
    int v = (t < NBUCKET) ? total[t] : 0;
    buf[t] = v;
    __syncthreads();
    #pragma unroll
    for (int d = 1; d < 256; d <<= 1) {
        int x = (t >= d) ? buf[t - d] : 0;
        __syncthreads();
        buf[t] += x;
        __syncthreads();
    }
    if (t < NBUCKET) basep[t] = buf[t] - v;         // exclusive
}

// 3) scatter packed edges into bucket-contiguous buffer (LDS cursors; base folded in)
__global__ __launch_bounds__(256) void k_scatter(const int* __restrict__ src,
                                                 const int* __restrict__ dst,
                                                 const int* __restrict__ off,
                                                 const int* __restrict__ basep,
                                                 uint32_t* __restrict__ ebuf) {
    __shared__ int cur[NBUCKET];
    int t = threadIdx.x, b = blockIdx.x;
    if (t < NBUCKET) cur[t] = off[b * NBUCKET + t] + basep[t];
    __syncthreads();
    const int e0 = b * CHUNK;
    for (int i = t; i < CHUNK; i += 256) {
        int d = dst[e0 + i];
        int s = src[e0 + i];                         // < 50000 < 2^16
        int p = atomicAdd(&cur[d >> 8], 1);
        ebuf[p] = ((uint32_t)(d & 255) << 16) | (uint32_t)s;
    }
}

// 4) per-bucket adjacency build: LDS counters, stores confined to 64KB region
__global__ __launch_bounds__(256) void k_build(const uint32_t* __restrict__ ebuf,
                                               const int* __restrict__ total,
                                               const int* __restrict__ basep,
                                               int* __restrict__ padded,
                                               int* __restrict__ cnt) {
    __shared__ int lcnt[256];
    int t = threadIdx.x, j = blockIdx.x;
    lcnt[t] = 0;
    __syncthreads();
    int b0 = basep[j], tot = total[j];
    for (int i = t; i < tot; i += 256) {
        uint32_t v = ebuf[b0 + i];
        int dl = (int)(v >> 16);
        int s  = (int)(v & 0xffffu);
        int p  = atomicAdd(&lcnt[dl], 1);
        if (p < PAD_CAP) padded[((size_t)j * 256 + dl) * PAD_CAP + p] = s;
    }
    __syncthreads();
    int node = j * 256 + t;
    if (node < N_NODES) cnt[node] = lcnt[t];
}

// ---------- canonicalize adjacency: bitonic sort each node's list across one wave ----------
// Multiset per node is deterministic; sorting makes the summation order (and bf16
// rounding) a deterministic function of the edge set, independent of build order.
__global__ __launch_bounds__(256) void k_sort_adj(int* __restrict__ padded,
                                                  const int* __restrict__ cnt) {
    int wid  = threadIdx.x >> 6;
    int lane = threadIdx.x & 63;
    int node = blockIdx.x * 4 + wid;
    if (node >= N_NODES) return;
    int deg = cnt[node];
    int m   = deg < PAD_CAP ? deg : PAD_CAP;
    int* lst = padded + (size_t)node * PAD_CAP;
    int v = (lane < m) ? lst[lane] : 0x7fffffff;   // pad sorts to the end
    #pragma unroll
    for (int k = 2; k <= 64; k <<= 1) {
        #pragma unroll
        for (int j = k >> 1; j > 0; j >>= 1) {
            int other  = __shfl_xor(v, j, 64);
            bool down  = (lane & k) != 0;
            bool lower = (lane & j) == 0;
            v = (lower ^ down) ? min(v, other) : max(v, other);
        }
    }
    if (lane < m) lst[lane] = v;                   // ascending neighbor ids
}

// ---------- per-graph node ranges from sorted batch (no atomics) ----------
__global__ __launch_bounds__(256) void k_gbounds(const int* __restrict__ batch,
                                                 int* __restrict__ gstart,
                                                 int* __restrict__ gend) {
    int i = blockIdx.x * 256 + threadIdx.x;
    if (i >= N_NODES) return;
    int g = batch[i];
    if (i == 0) gstart[g] = 0;
    int gn = (i + 1 < N_NODES) ? batch[i + 1] : -1;
    if (gn != g) {
        gend[g] = i + 1;
        if (gn >= 0) gstart[gn] = i + 1;
    }
}

// ---------- neighbor mean aggregation (one wave per node, 16-wide MLP) ----------
__global__ __launch_bounds__(256) void k_aggregate(const ushort* __restrict__ h_in,
                                                   const int* __restrict__ padded,
                                                   const int* __restrict__ cnt,
                                                   ushort* __restrict__ agg) {
    int wid  = threadIdx.x >> 6;
    int lane = threadIdx.x & 63;
    int node = blockIdx.x * 4 + wid;
    if (node >= N_NODES) return;
    int deg = cnt[node];
    int m   = deg < PAD_CAP ? deg : PAD_CAP;
    const int* lst = padded + (size_t)node * PAD_CAP;
    const uint32_t* hw = (const uint32_t*)h_in;   // 64 dwords per row
    float ax[4] = {0.f, 0.f, 0.f, 0.f};
    float ay[4] = {0.f, 0.f, 0.f, 0.f};
    for (int e = 0; e < m; e += 16) {
        int idx[16];
        uint32_t v[16];
        #pragma unroll
        for (int k = 0; k < 16; ++k) {
            int ek = e + k;
            idx[k] = lst[ek < m ? ek : m - 1];     // uniform clamp; dup loads hit cache
        }
        #pragma unroll
        for (int k = 0; k < 16; ++k)
            v[k] = hw[(size_t)idx[k] * 64 + lane]; // 16 independent 256B row loads in flight
        #pragma unroll
        for (int k = 0; k < 16; ++k) {
            uint32_t w = (e + k < m) ? v[k] : 0u;  // predicated tail (bf16 +0.0)
            ax[k & 3] += bf2f((ushort)(w & 0xffffu));
            ay[k & 3] += bf2f((ushort)(w >> 16));
        }
    }
    float axs = (ax[0] + ax[1]) + (ax[2] + ax[3]);
    float ays = (ay[0] + ay[1]) + (ay[2] + ay[3]);
    float inv = 1.0f / (float)(deg > 0 ? deg : 1);
    uint32_t o = (uint32_t)f2bf(axs * inv) | ((uint32_t)f2bf(ays * inv) << 16);
    ((uint32_t*)(agg + (size_t)node * DIM))[lane] = o;
}

// ---------- fused SAGE GEMM: h_out = relu([agg|h] @ [Wl;Wr] + bl) ----------
template <bool OUT_F32>
__global__ __launch_bounds__(256) void k_gemm(const ushort* __restrict__ agg,
                                              const ushort* __restrict__ h_in,
                                              const ushort* __restrict__ Wt,
                                              const float* __restrict__ bias,
                                              ushort* __restrict__ out_bf,
                                              float* __restrict__ out_f) {
    int wid   = threadIdx.x >> 6;
    int lane  = threadIdx.x & 63;
    int strip = blockIdx.x * 4 + wid;
    if (strip >= N_STRIPS) return;
    int r0   = strip * 16;
    int row  = lane & 15;
    int quad = lane >> 4;
    int mrow = r0 + row;

    // A fragments: lane holds A[m=lane&15][k=quad*8+j], j=0..7  (16B contiguous)
    short8 a[8];
    const ushort* arow = agg  + (size_t)mrow * DIM + quad * 8;
    const ushort* hrow = h_in + (size_t)mrow * DIM + quad * 8;
    #pragma unroll
    for (int ks = 0; ks < 4; ++ks) a[ks]     = *(const short8*)(arow + ks * 32);
    #pragma unroll
    for (int ks = 0; ks < 4; ++ks) a[4 + ks] = *(const short8*)(hrow + ks * 32);

    #pragma unroll
    for (int ct = 0; ct < 8; ++ct) {
        int col = ct * 16 + row;
        const ushort* wrow = Wt + (size_t)col * K2 + quad * 8;
        floatx4 acc = {0.f, 0.f, 0.f, 0.f};
        #pragma unroll
        for (int ks = 0; ks < 8; ++ks) {
            short8 b = *(const short8*)(wrow + ks * 32);
            acc = __builtin_amdgcn_mfma_f32_16x16x32_bf16(a[ks], b, acc, 0, 0, 0);
        }
        float bv = bias[col];
        #pragma unroll
        for (int r = 0; r < 4; ++r) {
            int m = r0 + quad * 4 + r;           // C/D: col=lane&15, row=quad*4+reg
            float v = acc[r] + bv;
            v = v > 0.f ? v : 0.f;
            if (OUT_F32) out_f[(size_t)m * DIM + col] = v;
            else         out_bf[(size_t)m * DIM + col] = f2bf(v);
        }
    }
}

// ---------- mean/max readout (batch sorted -> run-length flush) ----------
__global__ __launch_bounds__(128) void k_readout(const float* __restrict__ h,
                                                 const int* __restrict__ batch,
                                                 float* __restrict__ out) {
    int d  = threadIdx.x;                 // 0..127
    int n0 = blockIdx.x * 128;
    int n1 = min(n0 + 128, N_NODES);
    int cur = -1; float sum = 0.f, mx = 0.f;
    for (int i = n0; i < n1; ++i) {
        int g = batch[i];                 // block-uniform
        if (g != cur) {
            if (cur >= 0) {
                atomicAdd(&out[cur * 2 * DIM + d], sum);
                atomicMax((int*)&out[cur * 2 * DIM + DIM + d], __float_as_int(mx));
            }
            cur = g; sum = 0.f; mx = 0.f;
        }
        float v = h[(size_t)i * DIM + d];
        sum += v; mx = fmaxf(mx, v);
    }
    if (cur >= 0) {
        atomicAdd(&out[cur * 2 * DIM + d], sum);
        atomicMax((int*)&out[cur * 2 * DIM + DIM + d], __float_as_int(mx));
    }
}

__global__ __launch_bounds__(256) void k_finalize(float* __restrict__ out,
                                                  const int* __restrict__ gstart,
                                                  const int* __restrict__ gend) {
    int i = blockIdx.x * 256 + threadIdx.x;
    if (i < N_GRAPHS * DIM) {
        int g = i / DIM, d = i % DIM;
        int c = gend[g] - gstart[g];
        out[g * 2 * DIM + d] /= (float)(c > 0 ? c : 1);
    }
}

extern "C" void kernel_launch(void* const* d_in, const int* in_sizes, int n_in,
                              void* d_out, int out_size, void* d_ws, size_t ws_size,
                              hipStream_t stream) {
    const float* x     = (const float*)d_in[0];
    const int*   ei    = (const int*)d_in[1];
    const int*   src   = ei;
    const int*   dst   = ei + N_EDGES;
    const int*   batch = (const int*)d_in[2];
    const float* Wl[3] = {(const float*)d_in[3], (const float*)d_in[6], (const float*)d_in[9]};
    const float* bl[3] = {(const float*)d_in[4], (const float*)d_in[7], (const float*)d_in[10]};
    const float* Wr[3] = {(const float*)d_in[5], (const float*)d_in[8], (const float*)d_in[11]};
    float* out = (float*)d_out;

    char* base = (char*)d_ws;
    size_t o = 0;
    auto alloc = [&](size_t b) -> char* {
        char* p = base + o;
        o = (o + b + 255) & ~(size_t)255;
        return p;
    };
    int*     gstart = (int*)alloc((size_t)N_GRAPHS * 4);
    int*     gend   = (int*)alloc((size_t)N_GRAPHS * 4);
    size_t   zero_bytes = o;                      // gstart+gend contiguous
    int*     cnt    = (int*)alloc((size_t)N_NODES * 4);
    int*     counts = (int*)alloc((size_t)NCHUNK * NBUCKET * 4);
    int*     offs   = (int*)alloc((size_t)NCHUNK * NBUCKET * 4);
    int*     total  = (int*)alloc((size_t)NBUCKET * 4);
    int*     basep  = (int*)alloc((size_t)NBUCKET * 4);
    uint32_t* ebuf  = (uint32_t*)alloc((size_t)N_EDGES * 4);
    int*     padded = (int*)alloc((size_t)N_NODES * PAD_CAP * 4);    // 12.8 MB
    ushort*  xb     = (ushort*)alloc((size_t)N_NODES * DIM * 2);
    ushort*  ha     = (ushort*)alloc((size_t)N_NODES * DIM * 2);
    ushort*  hb     = (ushort*)alloc((size_t)N_NODES * DIM * 2);
    ushort*  agg    = (ushort*)alloc((size_t)N_NODES * DIM * 2);
    float*   h3     = (float*)alloc((size_t)N_NODES * DIM * 4);
    ushort*  Wt     = (ushort*)alloc((size_t)3 * DIM * K2 * 2);
    (void)ws_size; (void)n_in; (void)in_sizes;

    hipMemsetAsync(base, 0, zero_bytes, stream);
    hipMemsetAsync(d_out, 0, (size_t)out_size * 4, stream);

    k_convert_x<<<(N_NODES * DIM / 4 + 255) / 256, 256, 0, stream>>>(x, xb);
    k_prep_w_all<<<(3 * DIM * K2 + 255) / 256, 256, 0, stream>>>(
        Wl[0], Wr[0], Wl[1], Wr[1], Wl[2], Wr[2], Wt);

    k_hist<<<NCHUNK, 256, 0, stream>>>(dst, counts);
    k_scan_col<<<NBUCKET, 256, 0, stream>>>(counts, offs, total);
    k_scan_total<<<1, 256, 0, stream>>>(total, basep);
    k_scatter<<<NCHUNK, 256, 0, stream>>>(src, dst, offs, basep, ebuf);
    k_build<<<NBUCKET, 256, 0, stream>>>(ebuf, total, basep, padded, cnt);
    k_sort_adj<<<(N_NODES + 3) / 4, 256, 0, stream>>>(padded, cnt);
    k_gbounds<<<(N_NODES + 255) / 256, 256, 0, stream>>>(batch, gstart, gend);

    const int aggGrid  = (N_NODES + 3) / 4;
    const int gemmGrid = (N_STRIPS + 3) / 4;

    // layer 0
    k_aggregate<<<aggGrid, 256, 0, stream>>>(xb, padded, cnt, agg);
    k_gemm<false><<<gemmGrid, 256, 0, stream>>>(agg, xb, Wt, bl[0], ha, nullptr);
    // layer 1
    k_aggregate<<<aggGrid, 256, 0, stream>>>(ha, padded, cnt, agg);
    k_gemm<false><<<gemmGrid, 256, 0, stream>>>(agg, ha, Wt + DIM * K2, bl[1], hb, nullptr);
    // layer 2 (fp32 output for readout accuracy)
    k_aggregate<<<aggGrid, 256, 0, stream>>>(hb, padded, cnt, agg);
    k_gemm<true><<<gemmGrid, 256, 0, stream>>>(agg, hb, Wt + 2 * DIM * K2, bl[2], nullptr, h3);

    k_readout<<<(N_NODES + 127) / 128, 128, 0, stream>>>(h3, batch, out);
    k_finalize<<<(N_GRAPHS * DIM + 255) / 256, 256, 0, stream>>>(out, gstart, gend);
}

// Round 7
// 365.086 us; speedup vs baseline: 1.1900x; 1.0587x over previous
//
#include <hip/hip_runtime.h>
#include <hip/hip_bf16.h>
#include <stdint.h>

#define N_NODES  50000
#define N_GRAPHS 256
#define DIM      128
#define N_EDGES  800000
#define K2       256            // fused K = [agg | h]
#define N_STRIPS (N_NODES / 16) // 3125, exact
#define PAD_CAP  64             // max degree slack (mean 16; fixed edge list, no overflow)
#define NBUCKET  196            // ceil(50000/256) buckets of 256 nodes (bucket = dst>>8)
#define NCHUNK   256            // edge chunks
#define CHUNK    3125           // NCHUNK*CHUNK == N_EDGES exactly

typedef __attribute__((ext_vector_type(8))) short  short8;
typedef __attribute__((ext_vector_type(4))) float  floatx4;

__device__ __forceinline__ ushort f2bf(float f) {
    union { float f; uint32_t u; } c; c.f = f;
    uint32_t u = c.u;
    return (ushort)((u + 0x7fffu + ((u >> 16) & 1u)) >> 16);  // RNE
}
__device__ __forceinline__ float bf2f(ushort b) {
    union { uint32_t u; float f; } c; c.u = ((uint32_t)b) << 16;
    return c.f;
}

// ---------- prep: fp32 x -> bf16 ----------
__global__ __launch_bounds__(256) void k_convert_x(const float* __restrict__ x,
                                                   ushort* __restrict__ xb) {
    int i = blockIdx.x * 256 + threadIdx.x;          // float4 index
    const int n4 = N_NODES * DIM / 4;
    if (i < n4) {
        float4 v = ((const float4*)x)[i];
        uint32_t lo = (uint32_t)f2bf(v.x) | ((uint32_t)f2bf(v.y) << 16);
        uint32_t hi = (uint32_t)f2bf(v.z) | ((uint32_t)f2bf(v.w) << 16);
        ((uint2*)xb)[i] = make_uint2(lo, hi);
    }
}

// ---------- prep: all 3 layers' Wt[n][k] = bf16( k<128 ? Wl[k][n] : Wr[k-128][n] ) ----------
__global__ __launch_bounds__(256) void k_prep_w_all(const float* __restrict__ Wl0, const float* __restrict__ Wr0,
                                                    const float* __restrict__ Wl1, const float* __restrict__ Wr1,
                                                    const float* __restrict__ Wl2, const float* __restrict__ Wr2,
                                                    ushort* __restrict__ Wt) {   // 3 * DIM * K2
    int i = blockIdx.x * 256 + threadIdx.x;
    if (i < 3 * DIM * K2) {
        int layer = i / (DIM * K2);
        int j = i % (DIM * K2);
        int n = j / K2, k = j % K2;
        const float* Wl = (layer == 0) ? Wl0 : (layer == 1) ? Wl1 : Wl2;
        const float* Wr = (layer == 0) ? Wr0 : (layer == 1) ? Wr1 : Wr2;
        float v = (k < DIM) ? Wl[k * DIM + n] : Wr[(k - DIM) * DIM + n];
        Wt[i] = f2bf(v);
    }
}

// ---------- radix bucket build (no global atomics) ----------
__global__ __launch_bounds__(256) void k_hist(const int* __restrict__ dst,
                                              int* __restrict__ counts) {  // [NCHUNK][NBUCKET]
    __shared__ int hist[NBUCKET];
    int t = threadIdx.x, b = blockIdx.x;
    if (t < NBUCKET) hist[t] = 0;
    __syncthreads();
    const int e0 = b * CHUNK;
    for (int i = t; i < CHUNK; i += 256)
        atomicAdd(&hist[dst[e0 + i] >> 8], 1);
    __syncthreads();
    if (t < NBUCKET) counts[b * NBUCKET + t] = hist[t];
}

__global__ __launch_bounds__(256) void k_scan_col(const int* __restrict__ counts,
                                                  int* __restrict__ off,     // [NCHUNK][NBUCKET]
                                                  int* __restrict__ total) { // [NBUCKET]
    __shared__ int buf[256];
    int t = threadIdx.x, j = blockIdx.x;            // j < NBUCKET
    int v = counts[t * NBUCKET + j];
    buf[t] = v;
    __syncthreads();
    #pragma unroll
    for (int d = 1; d < 256; d <<= 1) {
        int x = (t >= d) ? buf[t - d] : 0;
        __syncthreads();
        buf[t] += x;
        __syncthreads();
    }
    off[t * NBUCKET + j] = buf[t] - v;              // exclusive within column
    if (t == 255) total[j] = buf[255];
}

__global__ __launch_bounds__(256) void k_scan_total(const int* __restrict__ total,
                                                    int* __restrict__ basep) {
    __shared__ int buf[256];
    int t = threadIdx.x;
    int v = (t < NBUCKET) ? total[t] : 0;
    buf[t] = v;
    __syncthreads();
    #pragma unroll
    for (int d = 1; d < 256; d <<= 1) {
        int x = (t >= d) ? buf[t - d] : 0;
        __syncthreads();
        buf[t] += x;
        __syncthreads();
    }
    if (t < NBUCKET) basep[t] = buf[t] - v;         // exclusive
}

__global__ __launch_bounds__(256) void k_scatter(const int* __restrict__ src,
                                                 const int* __restrict__ dst,
                                                 const int* __restrict__ off,
                                                 const int* __restrict__ basep,
                                                 uint32_t* __restrict__ ebuf) {
    __shared__ int cur[NBUCKET];
    int t = threadIdx.x, b = blockIdx.x;
    if (t < NBUCKET) cur[t] = off[b * NBUCKET + t] + basep[t];
    __syncthreads();
    const int e0 = b * CHUNK;
    for (int i = t; i < CHUNK; i += 256) {
        int d = dst[e0 + i];
        int s = src[e0 + i];                         // < 50000 < 2^16
        int p = atomicAdd(&cur[d >> 8], 1);
        ebuf[p] = ((uint32_t)(d & 255) << 16) | (uint32_t)s;
    }
}

__global__ __launch_bounds__(256) void k_build(const uint32_t* __restrict__ ebuf,
                                               const int* __restrict__ total,
                                               const int* __restrict__ basep,
                                               int* __restrict__ padded,
                                               int* __restrict__ cnt) {
    __shared__ int lcnt[256];
    int t = threadIdx.x, j = blockIdx.x;
    lcnt[t] = 0;
    __syncthreads();
    int b0 = basep[j], tot = total[j];
    for (int i = t; i < tot; i += 256) {
        uint32_t v = ebuf[b0 + i];
        int dl = (int)(v >> 16);
        int s  = (int)(v & 0xffffu);
        int p  = atomicAdd(&lcnt[dl], 1);
        if (p < PAD_CAP) padded[((size_t)j * 256 + dl) * PAD_CAP + p] = s;
    }
    __syncthreads();
    int node = j * 256 + t;
    if (node < N_NODES) cnt[node] = lcnt[t];
}

// ---------- canonicalize adjacency: bitonic sort each node's list across one wave ----------
// Multiset per node is deterministic; sorting makes the summation order (and bf16
// rounding) a deterministic function of the edge set, independent of build order.
__global__ __launch_bounds__(256) void k_sort_adj(int* __restrict__ padded,
                                                  const int* __restrict__ cnt) {
    int wid  = threadIdx.x >> 6;
    int lane = threadIdx.x & 63;
    int node = blockIdx.x * 4 + wid;
    if (node >= N_NODES) return;
    int deg = cnt[node];
    int m   = deg < PAD_CAP ? deg : PAD_CAP;
    int* lst = padded + (size_t)node * PAD_CAP;
    int v = (lane < m) ? lst[lane] : 0x7fffffff;   // pad sorts to the end
    #pragma unroll
    for (int k = 2; k <= 64; k <<= 1) {
        #pragma unroll
        for (int j = k >> 1; j > 0; j >>= 1) {
            int other  = __shfl_xor(v, j, 64);
            bool down  = (lane & k) != 0;
            bool lower = (lane & j) == 0;
            v = (lower ^ down) ? min(v, other) : max(v, other);
        }
    }
    if (lane < m) lst[lane] = v;                   // ascending neighbor ids
}

// ---------- per-graph node ranges from sorted batch (no atomics) ----------
__global__ __launch_bounds__(256) void k_gbounds(const int* __restrict__ batch,
                                                 int* __restrict__ gstart,
                                                 int* __restrict__ gend) {
    int i = blockIdx.x * 256 + threadIdx.x;
    if (i >= N_NODES) return;
    int g = batch[i];
    if (i == 0) gstart[g] = 0;
    int gn = (i + 1 < N_NODES) ? batch[i + 1] : -1;
    if (gn != g) {
        gend[g] = i + 1;
        if (gn >= 0) gstart[gn] = i + 1;
    }
}

// ---------- fused SAGE layer: gather-mean into LDS, then MFMA ----------
// Workgroup = one 16-row strip. Phase 1: wave w aggregates nodes w*4..w*4+3 into
// LDS bf16 tile. Phase 2: A = [LDS agg | global h] frags, B = Wt, 2 col-tiles/wave.
template <bool OUT_F32>
__global__ __launch_bounds__(256) void k_layer(const ushort* __restrict__ h_in,
                                               const int* __restrict__ padded,
                                               const int* __restrict__ cnt,
                                               const ushort* __restrict__ Wt,
                                               const float* __restrict__ bias,
                                               ushort* __restrict__ out_bf,
                                               float* __restrict__ out_f) {
    __shared__ ushort sAgg[16 * DIM];             // 4 KB
    int wid  = threadIdx.x >> 6;
    int lane = threadIdx.x & 63;
    int r0   = blockIdx.x * 16;
    const uint32_t* hw = (const uint32_t*)h_in;   // 64 dwords per row

    // ---- phase 1: gather-mean 4 nodes per wave ----
    for (int q = 0; q < 4; ++q) {
        int node = r0 + wid * 4 + q;
        int deg = cnt[node];
        int m   = deg < PAD_CAP ? deg : PAD_CAP;
        const int* lst = padded + (size_t)node * PAD_CAP;
        float ax[4] = {0.f, 0.f, 0.f, 0.f};
        float ay[4] = {0.f, 0.f, 0.f, 0.f};
        for (int e = 0; e < m; e += 16) {
            int idx[16];
            uint32_t v[16];
            #pragma unroll
            for (int k = 0; k < 16; ++k) {
                int ek = e + k;
                idx[k] = lst[ek < m ? ek : m - 1];     // uniform clamp; dup loads hit cache
            }
            #pragma unroll
            for (int k = 0; k < 16; ++k)
                v[k] = hw[(size_t)idx[k] * 64 + lane]; // 16 row loads in flight
            #pragma unroll
            for (int k = 0; k < 16; ++k) {
                uint32_t w = (e + k < m) ? v[k] : 0u;  // predicated tail (bf16 +0.0)
                ax[k & 3] += bf2f((ushort)(w & 0xffffu));
                ay[k & 3] += bf2f((ushort)(w >> 16));
            }
        }
        float axs = (ax[0] + ax[1]) + (ax[2] + ax[3]);
        float ays = (ay[0] + ay[1]) + (ay[2] + ay[3]);
        float inv = 1.0f / (float)(deg > 0 ? deg : 1);
        uint32_t o = (uint32_t)f2bf(axs * inv) | ((uint32_t)f2bf(ays * inv) << 16);
        ((uint32_t*)(sAgg + (wid * 4 + q) * DIM))[lane] = o;
    }
    __syncthreads();

    // ---- phase 2: MFMA. A-frags: lane holds A[m=lane&15][k=quad*8+j] ----
    int row  = lane & 15;
    int quad = lane >> 4;
    short8 a[8];
    const ushort* srow = sAgg + row * DIM + quad * 8;
    #pragma unroll
    for (int ks = 0; ks < 4; ++ks) a[ks] = *(const short8*)(srow + ks * 32);  // LDS b128
    const ushort* hrow = h_in + (size_t)(r0 + row) * DIM + quad * 8;
    #pragma unroll
    for (int ks = 0; ks < 4; ++ks) a[4 + ks] = *(const short8*)(hrow + ks * 32);

    #pragma unroll
    for (int c = 0; c < 2; ++c) {
        int ct  = wid * 2 + c;                     // 4 waves x 2 = 8 col-tiles
        int col = ct * 16 + row;
        const ushort* wrow = Wt + (size_t)col * K2 + quad * 8;
        floatx4 acc = {0.f, 0.f, 0.f, 0.f};
        #pragma unroll
        for (int ks = 0; ks < 8; ++ks) {
            short8 b = *(const short8*)(wrow + ks * 32);
            acc = __builtin_amdgcn_mfma_f32_16x16x32_bf16(a[ks], b, acc, 0, 0, 0);
        }
        float bv = bias[col];
        #pragma unroll
        for (int r = 0; r < 4; ++r) {
            int m = r0 + quad * 4 + r;             // C/D: col=lane&15, row=quad*4+reg
            float v = acc[r] + bv;
            v = v > 0.f ? v : 0.f;
            if (OUT_F32) out_f[(size_t)m * DIM + col] = v;
            else         out_bf[(size_t)m * DIM + col] = f2bf(v);
        }
    }
}

// ---------- mean/max readout (batch sorted -> run-length flush) ----------
__global__ __launch_bounds__(128) void k_readout(const float* __restrict__ h,
                                                 const int* __restrict__ batch,
                                                 float* __restrict__ out) {
    int d  = threadIdx.x;                 // 0..127
    int n0 = blockIdx.x * 128;
    int n1 = min(n0 + 128, N_NODES);
    int cur = -1; float sum = 0.f, mx = 0.f;
    for (int i = n0; i < n1; ++i) {
        int g = batch[i];                 // block-uniform
        if (g != cur) {
            if (cur >= 0) {
                atomicAdd(&out[cur * 2 * DIM + d], sum);
                atomicMax((int*)&out[cur * 2 * DIM + DIM + d], __float_as_int(mx));
            }
            cur = g; sum = 0.f; mx = 0.f;
        }
        float v = h[(size_t)i * DIM + d];
        sum += v; mx = fmaxf(mx, v);
    }
    if (cur >= 0) {
        atomicAdd(&out[cur * 2 * DIM + d], sum);
        atomicMax((int*)&out[cur * 2 * DIM + DIM + d], __float_as_int(mx));
    }
}

__global__ __launch_bounds__(256) void k_finalize(float* __restrict__ out,
                                                  const int* __restrict__ gstart,
                                                  const int* __restrict__ gend) {
    int i = blockIdx.x * 256 + threadIdx.x;
    if (i < N_GRAPHS * DIM) {
        int g = i / DIM, d = i % DIM;
        int c = gend[g] - gstart[g];
        out[g * 2 * DIM + d] /= (float)(c > 0 ? c : 1);
    }
}

extern "C" void kernel_launch(void* const* d_in, const int* in_sizes, int n_in,
                              void* d_out, int out_size, void* d_ws, size_t ws_size,
                              hipStream_t stream) {
    const float* x     = (const float*)d_in[0];
    const int*   ei    = (const int*)d_in[1];
    const int*   src   = ei;
    const int*   dst   = ei + N_EDGES;
    const int*   batch = (const int*)d_in[2];
    const float* Wl[3] = {(const float*)d_in[3], (const float*)d_in[6], (const float*)d_in[9]};
    const float* bl[3] = {(const float*)d_in[4], (const float*)d_in[7], (const float*)d_in[10]};
    const float* Wr[3] = {(const float*)d_in[5], (const float*)d_in[8], (const float*)d_in[11]};
    float* out = (float*)d_out;

    char* base = (char*)d_ws;
    size_t o = 0;
    auto alloc = [&](size_t b) -> char* {
        char* p = base + o;
        o = (o + b + 255) & ~(size_t)255;
        return p;
    };
    int*     gstart = (int*)alloc((size_t)N_GRAPHS * 4);
    int*     gend   = (int*)alloc((size_t)N_GRAPHS * 4);
    size_t   zero_bytes = o;                      // gstart+gend contiguous
    int*     cnt    = (int*)alloc((size_t)N_NODES * 4);
    int*     counts = (int*)alloc((size_t)NCHUNK * NBUCKET * 4);
    int*     offs   = (int*)alloc((size_t)NCHUNK * NBUCKET * 4);
    int*     total  = (int*)alloc((size_t)NBUCKET * 4);
    int*     basep  = (int*)alloc((size_t)NBUCKET * 4);
    uint32_t* ebuf  = (uint32_t*)alloc((size_t)N_EDGES * 4);
    int*     padded = (int*)alloc((size_t)N_NODES * PAD_CAP * 4);    // 12.8 MB
    ushort*  xb     = (ushort*)alloc((size_t)N_NODES * DIM * 2);
    ushort*  ha     = (ushort*)alloc((size_t)N_NODES * DIM * 2);
    ushort*  hb     = (ushort*)alloc((size_t)N_NODES * DIM * 2);
    float*   h3     = (float*)alloc((size_t)N_NODES * DIM * 4);
    ushort*  Wt     = (ushort*)alloc((size_t)3 * DIM * K2 * 2);
    (void)ws_size; (void)n_in; (void)in_sizes;

    hipMemsetAsync(base, 0, zero_bytes, stream);
    hipMemsetAsync(d_out, 0, (size_t)out_size * 4, stream);

    k_convert_x<<<(N_NODES * DIM / 4 + 255) / 256, 256, 0, stream>>>(x, xb);
    k_prep_w_all<<<(3 * DIM * K2 + 255) / 256, 256, 0, stream>>>(
        Wl[0], Wr[0], Wl[1], Wr[1], Wl[2], Wr[2], Wt);

    k_hist<<<NCHUNK, 256, 0, stream>>>(dst, counts);
    k_scan_col<<<NBUCKET, 256, 0, stream>>>(counts, offs, total);
    k_scan_total<<<1, 256, 0, stream>>>(total, basep);
    k_scatter<<<NCHUNK, 256, 0, stream>>>(src, dst, offs, basep, ebuf);
    k_build<<<NBUCKET, 256, 0, stream>>>(ebuf, total, basep, padded, cnt);
    k_sort_adj<<<(N_NODES + 3) / 4, 256, 0, stream>>>(padded, cnt);
    k_gbounds<<<(N_NODES + 255) / 256, 256, 0, stream>>>(batch, gstart, gend);

    // fused layers (one kernel each)
    k_layer<false><<<N_STRIPS, 256, 0, stream>>>(xb, padded, cnt, Wt,              bl[0], ha, nullptr);
    k_layer<false><<<N_STRIPS, 256, 0, stream>>>(ha, padded, cnt, Wt + DIM * K2,   bl[1], hb, nullptr);
    k_layer<true ><<<N_STRIPS, 256, 0, stream>>>(hb, padded, cnt, Wt + 2 * DIM * K2, bl[2], nullptr, h3);

    k_readout<<<(N_NODES + 127) / 128, 128, 0, stream>>>(h3, batch, out);
    k_finalize<<<(N_GRAPHS * DIM + 255) / 256, 256, 0, stream>>>(out, gstart, gend);
}